// Round 3
// baseline (665.931 us; speedup 1.0000x reference)
//
#include <hip/hip_runtime.h>

typedef __bf16 bf16_t;
typedef bf16_t bf16x4 __attribute__((ext_vector_type(4)));
typedef bf16_t bf16x8 __attribute__((ext_vector_type(8)));
typedef float floatx4 __attribute__((ext_vector_type(4)));

#define EPSF 1e-5f
#define DEV static __device__ __forceinline__

// ---------------------------------------------------------------------------
// K0: swizzle weight matrices (f32 [K][128]) into B-fragment order, bf16.
// sw[((t*nK + s)*64 + l)*8 + j] = W[(s*32 + (l>>4)*8 + j)*128 + (t*16 + (l&15))]
// ---------------------------------------------------------------------------
__global__ __launch_bounds__(256) void k_prep(
    const float* __restrict__ W_in, const float* __restrict__ W_ctx1,
    const float* __restrict__ W_ctx2, const float* __restrict__ W_m1,
    const float* __restrict__ W_m2, bf16_t* __restrict__ sw)
{
    int idx = blockIdx.x * 256 + threadIdx.x;   // grid sized to exactly 98304
    const float* W; int base, ks;
    if (idx < 16384)      { W = W_in;   base = 0;     ks = 2; }
    else if (idx < 49152) { W = W_ctx1; base = 16384; ks = 3; }
    else if (idx < 65536) { W = W_ctx2; base = 49152; ks = 2; }
    else if (idx < 81920) { W = W_m1;   base = 65536; ks = 2; }
    else                  { W = W_m2;   base = 81920; ks = 2; }
    int local = idx - base;
    int j = local & 7, l = (local >> 3) & 63, rest = local >> 9;
    int s = rest & ((1 << ks) - 1), t = rest >> ks;
    int k = s * 32 + (l >> 4) * 8 + j;
    int n = t * 16 + (l & 15);
    sw[idx] = (bf16_t)W[k * 128 + n];
}

// ---------------------------------------------------------------------------
// CSR construction: zero -> histogram -> block scan -> top scan -> add ->
// bucket. All tiny (<10 us combined).
// ---------------------------------------------------------------------------
__global__ void k_zero(int* __restrict__ p, int n) {
    int i = blockIdx.x * 256 + threadIdx.x;
    if (i < n) p[i] = 0;
}

__global__ void k_hist(const int* __restrict__ wi, int* __restrict__ deg, int E) {
    int i = blockIdx.x * 256 + threadIdx.x;
    if (i < E) atomicAdd(&deg[wi[i]], 1);
}

// in-place: a[] -> block-local exclusive scan; bsum[blk] = block total
__global__ __launch_bounds__(256) void k_scan_block(int* __restrict__ a,
                                                    int* __restrict__ bsum, int n) {
    __shared__ int wsum[4];
    int tid = threadIdx.x, lane = tid & 63, wv = tid >> 6;
    int base = blockIdx.x * 1024 + tid * 4;
    int v[4];
#pragma unroll
    for (int i = 0; i < 4; ++i) v[i] = (base + i < n) ? a[base + i] : 0;
    int tsum = v[0] + v[1] + v[2] + v[3];
    int sc = tsum;
#pragma unroll
    for (int d = 1; d < 64; d <<= 1) {
        int o = __shfl_up(sc, d);
        if (lane >= d) sc += o;
    }
    if (lane == 63) wsum[wv] = sc;
    __syncthreads();
    int wadd = 0;
    for (int w = 0; w < wv; ++w) wadd += wsum[w];
    int run = sc - tsum + wadd;   // exclusive for this thread's first element
#pragma unroll
    for (int i = 0; i < 4; ++i) {
        int t = v[i];
        if (base + i < n) a[base + i] = run;
        run += t;
    }
    if (tid == 255) bsum[blockIdx.x] = wadd + sc;
}

// single block, exclusive scan of <=128 block sums
__global__ __launch_bounds__(128) void k_scan_top(int* __restrict__ bsum, int nb) {
    __shared__ int s[128];
    int tid = threadIdx.x;
    int v = (tid < nb) ? bsum[tid] : 0;
    s[tid] = v;
    __syncthreads();
    for (int d = 1; d < 128; d <<= 1) {
        int t = (tid >= d) ? s[tid - d] : 0;
        __syncthreads();
        s[tid] += t;
        __syncthreads();
    }
    if (tid < nb) bsum[tid] = s[tid] - v;
}

__global__ void k_scan_add(int* __restrict__ a, int* __restrict__ cursor,
                           const int* __restrict__ bsum, int n) {
    int i = blockIdx.x * 256 + threadIdx.x;
    if (i < n) { int v = a[i] + bsum[i >> 10]; a[i] = v; cursor[i] = v; }
}

__global__ void k_bucket(const int* __restrict__ wi, int* __restrict__ cursor,
                         int* __restrict__ elist, int E) {
    int e = blockIdx.x * 256 + threadIdx.x;
    if (e < E) { int p = atomicAdd(&cursor[wi[e]], 1); elist[p] = e; }
}

// GroupNorm over 128 channels per row, on MFMA C-layout accumulators.
// acc[t][rr] holds element (row = (lane>>4)*4+rr, col = t*16 + (lane&15)).
DEV void gn_rows(floatx4* acc, int lane, const float* __restrict__ gamma,
                 const float* __restrict__ beta, bool do_relu)
{
    int m = lane & 15;
    float s1[4] = {0.f,0.f,0.f,0.f}, s2[4] = {0.f,0.f,0.f,0.f};
#pragma unroll
    for (int t = 0; t < 8; ++t)
#pragma unroll
        for (int rr = 0; rr < 4; ++rr) { float v = acc[t][rr]; s1[rr] += v; s2[rr] += v*v; }
#pragma unroll
    for (int mask = 1; mask <= 8; mask <<= 1)
#pragma unroll
        for (int rr = 0; rr < 4; ++rr) {
            s1[rr] += __shfl_xor(s1[rr], mask);
            s2[rr] += __shfl_xor(s2[rr], mask);
        }
    float mean[4], inv[4];
#pragma unroll
    for (int rr = 0; rr < 4; ++rr) {
        mean[rr] = s1[rr] * (1.f/128.f);
        float var = s2[rr] * (1.f/128.f) - mean[rr]*mean[rr];
        inv[rr] = rsqrtf(var + EPSF);
    }
#pragma unroll
    for (int t = 0; t < 8; ++t) {
        int n = t*16 + m;
        float ga = gamma[n], be = beta[n];
#pragma unroll
        for (int rr = 0; rr < 4; ++rr) {
            float v = (acc[t][rr] - mean[rr]) * inv[rr] * ga + be;
            acc[t][rr] = do_relu ? fmaxf(v, 0.f) : v;
        }
    }
}

// ---------------------------------------------------------------------------
// K1: tf = target_feat @ W_in   (f32 out into workspace)
// ---------------------------------------------------------------------------
__global__ __launch_bounds__(256) void k_gemm_in(
    const float* __restrict__ tfeat, const bf16_t* __restrict__ swW,
    float* __restrict__ tf, int Nt)
{
    __shared__ alignas(16) bf16_t sA[4][2048];    // per-wave A tile (A-frag order)
    int tid = threadIdx.x, lane = tid & 63, wave = tid >> 6;

    int tb = (blockIdx.x * 4 + wave) * 16;
    int r = lane >> 2, cb = (lane & 3) * 32;
    int grow = tb + r;
    bool rv = grow < Nt;
    const float4* src = (const float4*)(tfeat + (size_t)(rv ? grow : 0) * 128 + cb);
#pragma unroll
    for (int i = 0; i < 8; ++i) {
        float4 v = rv ? src[i] : make_float4(0.f,0.f,0.f,0.f);
        int k = cb + 4*i;
        int s = k >> 5, q = (k >> 3) & 3, j = k & 7;
        bf16x4 pk = { (bf16_t)v.x, (bf16_t)v.y, (bf16_t)v.z, (bf16_t)v.w };
        *(bf16x4*)&sA[wave][(s*64 + q*16 + r)*8 + j] = pk;
    }
    __syncthreads();
    int m = lane & 15, g = lane >> 4;
    bf16x8 aF[4];
#pragma unroll
    for (int s = 0; s < 4; ++s) aF[s] = *(const bf16x8*)&sA[wave][(s*64 + lane)*8];
#pragma unroll
    for (int t = 0; t < 8; ++t) {
        floatx4 a = {0.f,0.f,0.f,0.f};
#pragma unroll
        for (int s = 0; s < 4; ++s) {
            bf16x8 bF = *(const bf16x8*)&swW[((t*4+s)*64 + lane)*8];
            a = __builtin_amdgcn_mfma_f32_16x16x32_bf16(aF[s], bF, a, 0, 0, 0);
        }
#pragma unroll
        for (int rr = 0; rr < 4; ++rr) {
            int row = tb + g*4 + rr;
            if (row < Nt) tf[(size_t)row*128 + t*16 + m] = a[rr];
        }
    }
}

// ---------------------------------------------------------------------------
// K2: per-edge MLP -> ctx[E,128] bf16 (plain stores; no atomics).
// ---------------------------------------------------------------------------
__global__ __launch_bounds__(256) void k_edge(
    const float* __restrict__ cfeat, const float* __restrict__ cpose,
    const float* __restrict__ tpose, const int* __restrict__ hi,
    const int* __restrict__ wi, const float* __restrict__ W_rp,
    const float* __restrict__ b_rp, const float* __restrict__ g_ctx,
    const float* __restrict__ be_ctx, const bf16_t* __restrict__ swC1,
    const bf16_t* __restrict__ swC2, bf16_t* __restrict__ ctx, int E)
{
    __shared__ alignas(16) bf16_t sA[4][4096];    // per-wave [16 x 256] A-frag order
    int tid = threadIdx.x, lane = tid & 63, wave = tid >> 6;

    int tb = (blockIdx.x * 4 + wave) * 16;
    int r = lane >> 2, cb = (lane & 3) * 32;
    int e = min(tb + r, E - 1);
    int ci = hi[e], ti = wi[e];
    // context features -> k in [0,128)
    const float4* src = (const float4*)(cfeat + (size_t)ci * 128 + cb);
#pragma unroll
    for (int i = 0; i < 8; ++i) {
        float4 v = src[i];
        int k = cb + 4*i;
        int s = k >> 5, q = (k >> 3) & 3, j = k & 7;
        bf16x4 pk = { (bf16_t)v.x, (bf16_t)v.y, (bf16_t)v.z, (bf16_t)v.w };
        *(bf16x4*)&sA[wave][(s*64 + q*16 + r)*8 + j] = pk;
    }
    // relpose MLP -> k in [128,256)
    float4 cp = ((const float4*)cpose)[ci];
    float4 tp = ((const float4*)tpose)[ti];
    float d0 = cp.x - tp.x, d1 = cp.y - tp.y, d2 = cp.z - tp.z, d3 = cp.w - tp.w;
#pragma unroll
    for (int i = 0; i < 8; ++i) {
        int c = cb + 4*i;
        float4 w0 = *(const float4*)(W_rp + c);
        float4 w1 = *(const float4*)(W_rp + 128 + c);
        float4 w2 = *(const float4*)(W_rp + 256 + c);
        float4 w3 = *(const float4*)(W_rp + 384 + c);
        float4 bb = *(const float4*)(b_rp + c);
        float o0 = fmaxf(d0*w0.x + d1*w1.x + d2*w2.x + d3*w3.x + bb.x, 0.f);
        float o1 = fmaxf(d0*w0.y + d1*w1.y + d2*w2.y + d3*w3.y + bb.y, 0.f);
        float o2 = fmaxf(d0*w0.z + d1*w1.z + d2*w2.z + d3*w3.z + bb.z, 0.f);
        float o3 = fmaxf(d0*w0.w + d1*w1.w + d2*w2.w + d3*w3.w + bb.w, 0.f);
        int k = 128 + c;
        int s = k >> 5, q = (k >> 3) & 3, j = k & 7;
        bf16x4 pk = { (bf16_t)o0, (bf16_t)o1, (bf16_t)o2, (bf16_t)o3 };
        *(bf16x4*)&sA[wave][(s*64 + q*16 + r)*8 + j] = pk;
    }
    __syncthreads();

    int m = lane & 15, g = lane >> 4;
    bf16x8 aF[8];
#pragma unroll
    for (int s = 0; s < 8; ++s) aF[s] = *(const bf16x8*)&sA[wave][(s*64 + lane)*8];
    floatx4 acc[8];
#pragma unroll
    for (int t = 0; t < 8; ++t) {
        floatx4 a = {0.f,0.f,0.f,0.f};
#pragma unroll
        for (int s = 0; s < 8; ++s) {
            bf16x8 bF = *(const bf16x8*)&swC1[(size_t)((t*8+s)*64 + lane)*8];
            a = __builtin_amdgcn_mfma_f32_16x16x32_bf16(aF[s], bF, a, 0, 0, 0);
        }
        acc[t] = a;
    }
    gn_rows(acc, lane, g_ctx, be_ctx, true);
    __syncthreads();
    // write h back into sA (A-frag order, K=128 region)
#pragma unroll
    for (int t = 0; t < 8; ++t) {
        int n = t*16 + m;
        int s = n >> 5, q = (n >> 3) & 3, j = n & 7;
#pragma unroll
        for (int rr = 0; rr < 4; ++rr)
            sA[wave][(s*64 + q*16 + (g*4+rr))*8 + j] = (bf16_t)acc[t][rr];
    }
    __syncthreads();
    bf16x8 aF2[4];
#pragma unroll
    for (int s = 0; s < 4; ++s) aF2[s] = *(const bf16x8*)&sA[wave][(s*64 + lane)*8];
#pragma unroll
    for (int t = 0; t < 8; ++t) {
        floatx4 a = {0.f,0.f,0.f,0.f};
#pragma unroll
        for (int s = 0; s < 4; ++s) {
            bf16x8 bF = *(const bf16x8*)&swC2[((t*4+s)*64 + lane)*8];
            a = __builtin_amdgcn_mfma_f32_16x16x32_bf16(aF2[s], bF, a, 0, 0, 0);
        }
#pragma unroll
        for (int rr = 0; rr < 4; ++rr) {
            int ee = tb + g*4 + rr;
            if (ee < E) ctx[(size_t)ee*128 + t*16 + m] = (bf16_t)a[rr];
        }
    }
}

// ---------------------------------------------------------------------------
// K3: per target row: tf += sum(ctx[CSR edges]); then
// out = relu(GN(relu(GN(relu(GN(tf)) @ W_m1)) @ W_m2) + identity)
// ---------------------------------------------------------------------------
__global__ __launch_bounds__(256) void k_out(
    const float* __restrict__ tf, const float* __restrict__ identity,
    const int* __restrict__ start, const int* __restrict__ cend,
    const int* __restrict__ elist, const bf16_t* __restrict__ ctx,
    const float* __restrict__ g_n, const float* __restrict__ be_n,
    const float* __restrict__ g_m1, const float* __restrict__ be_m1,
    const float* __restrict__ g_m2, const float* __restrict__ be_m2,
    const bf16_t* __restrict__ swM1, const bf16_t* __restrict__ swM2,
    float* __restrict__ out, int Nt)
{
    __shared__ alignas(16) bf16_t sA[4][2048];
    int tid = threadIdx.x, lane = tid & 63, wave = tid >> 6;

    int tb = (blockIdx.x*4 + wave)*16;
    int r = lane >> 2, cb = (lane & 3)*32;
    int grow = tb + r;
    bool rv = grow < Nt;
    const float4* src = (const float4*)(tf + (size_t)(rv ? grow : 0)*128 + cb);
    float vals[32];
#pragma unroll
    for (int i = 0; i < 8; ++i) {
        float4 v = rv ? src[i] : make_float4(0.f,0.f,0.f,0.f);
        vals[4*i+0]=v.x; vals[4*i+1]=v.y; vals[4*i+2]=v.z; vals[4*i+3]=v.w;
    }
    // CSR scatter-sum: add incoming edge ctx rows
    int s0 = rv ? start[grow] : 0;
    int s1 = rv ? cend[grow] : 0;
    for (int p = s0; p < s1; ++p) {
        int e = elist[p];
        const bf16x8* cp = (const bf16x8*)(ctx + (size_t)e*128 + cb);
#pragma unroll
        for (int i = 0; i < 4; ++i) {
            bf16x8 c8 = cp[i];
#pragma unroll
            for (int j = 0; j < 8; ++j) vals[8*i+j] += (float)c8[j];
        }
    }
    float ls = 0.f, lq = 0.f;
#pragma unroll
    for (int i = 0; i < 32; ++i) { ls += vals[i]; lq += vals[i]*vals[i]; }
    ls += __shfl_xor(ls,1); lq += __shfl_xor(lq,1);
    ls += __shfl_xor(ls,2); lq += __shfl_xor(lq,2);
    float mean = ls*(1.f/128.f);
    float inv = rsqrtf(lq*(1.f/128.f) - mean*mean + EPSF);
#pragma unroll
    for (int i = 0; i < 8; ++i) {
        int c = cb + 4*i;
        float4 ga = *(const float4*)(g_n + c);
        float4 be = *(const float4*)(be_n + c);
        float o0 = fmaxf((vals[4*i+0]-mean)*inv*ga.x + be.x, 0.f);
        float o1 = fmaxf((vals[4*i+1]-mean)*inv*ga.y + be.y, 0.f);
        float o2 = fmaxf((vals[4*i+2]-mean)*inv*ga.z + be.z, 0.f);
        float o3 = fmaxf((vals[4*i+3]-mean)*inv*ga.w + be.w, 0.f);
        int s = c >> 5, q = (c >> 3) & 3, j = c & 7;
        bf16x4 pk = { (bf16_t)o0, (bf16_t)o1, (bf16_t)o2, (bf16_t)o3 };
        *(bf16x4*)&sA[wave][(s*64 + q*16 + r)*8 + j] = pk;
    }
    __syncthreads();
    int m = lane & 15, g = lane >> 4;
    bf16x8 aF[4];
#pragma unroll
    for (int s = 0; s < 4; ++s) aF[s] = *(const bf16x8*)&sA[wave][(s*64 + lane)*8];
    floatx4 acc[8];
#pragma unroll
    for (int t = 0; t < 8; ++t) {
        floatx4 a = {0.f,0.f,0.f,0.f};
#pragma unroll
        for (int s = 0; s < 4; ++s) {
            bf16x8 bF = *(const bf16x8*)&swM1[((t*4+s)*64 + lane)*8];
            a = __builtin_amdgcn_mfma_f32_16x16x32_bf16(aF[s], bF, a, 0, 0, 0);
        }
        acc[t] = a;
    }
    gn_rows(acc, lane, g_m1, be_m1, true);
    __syncthreads();
#pragma unroll
    for (int t = 0; t < 8; ++t) {
        int n = t*16 + m;
        int s = n >> 5, q = (n >> 3) & 3, j = n & 7;
#pragma unroll
        for (int rr = 0; rr < 4; ++rr)
            sA[wave][(s*64 + q*16 + (g*4+rr))*8 + j] = (bf16_t)acc[t][rr];
    }
    __syncthreads();
#pragma unroll
    for (int s = 0; s < 4; ++s) aF[s] = *(const bf16x8*)&sA[wave][(s*64 + lane)*8];
#pragma unroll
    for (int t = 0; t < 8; ++t) {
        floatx4 a = {0.f,0.f,0.f,0.f};
#pragma unroll
        for (int s = 0; s < 4; ++s) {
            bf16x8 bF = *(const bf16x8*)&swM2[((t*4+s)*64 + lane)*8];
            a = __builtin_amdgcn_mfma_f32_16x16x32_bf16(aF[s], bF, a, 0, 0, 0);
        }
        acc[t] = a;
    }
    gn_rows(acc, lane, g_m2, be_m2, false);
#pragma unroll
    for (int t = 0; t < 8; ++t) {
        int n = t*16 + m;
#pragma unroll
        for (int rr = 0; rr < 4; ++rr) {
            int row = tb + g*4 + rr;
            if (row < Nt) {
                float v = acc[t][rr] + identity[(size_t)row*128 + n];
                out[(size_t)row*128 + n] = fmaxf(v, 0.f);
            }
        }
    }
}

// ---------------------------------------------------------------------------
extern "C" void kernel_launch(void* const* d_in, const int* in_sizes, int n_in,
                              void* d_out, int out_size, void* d_ws, size_t ws_size,
                              hipStream_t stream)
{
    const float* cfeat  = (const float*)d_in[0];
    const float* tfeat  = (const float*)d_in[1];
    const float* cpose  = (const float*)d_in[2];
    const float* tpose  = (const float*)d_in[3];
    const int*   hi     = (const int*)d_in[4];
    const int*   wi     = (const int*)d_in[5];
    const float* W_in   = (const float*)d_in[6];
    const float* W_rp   = (const float*)d_in[7];
    const float* b_rp   = (const float*)d_in[8];
    const float* W_ctx1 = (const float*)d_in[9];
    const float* g_ctx  = (const float*)d_in[10];
    const float* be_ctx = (const float*)d_in[11];
    const float* W_ctx2 = (const float*)d_in[12];
    const float* g_n    = (const float*)d_in[13];
    const float* be_n   = (const float*)d_in[14];
    const float* W_m1   = (const float*)d_in[15];
    const float* g_m1   = (const float*)d_in[16];
    const float* be_m1  = (const float*)d_in[17];
    const float* W_m2   = (const float*)d_in[18];
    const float* g_m2   = (const float*)d_in[19];
    const float* be_m2  = (const float*)d_in[20];

    int Nt = in_sizes[1] / 128;
    int E  = in_sizes[4];
    float* outp = (float*)d_out;

    // ---- workspace carve-up (aligned to 256 B per section) ----
    char* w = (char*)d_ws;
    size_t off = 0;
    auto alloc = [&](size_t bytes) { char* p = w + off;
        off = (off + bytes + 255) & ~(size_t)255; return p; };
    float*  tf     = (float*) alloc((size_t)Nt * 128 * sizeof(float));
    bf16_t* sw     = (bf16_t*)alloc(98304 * sizeof(bf16_t));
    bf16_t* ctx    = (bf16_t*)alloc((size_t)E * 128 * sizeof(bf16_t));
    int*    start  = (int*)   alloc((size_t)Nt * sizeof(int));
    int*    cursor = (int*)   alloc((size_t)Nt * sizeof(int));
    int*    elist  = (int*)   alloc((size_t)E * sizeof(int));
    int*    bsum   = (int*)   alloc(128 * sizeof(int));

    bf16_t* swIn = sw;
    bf16_t* swC1 = sw + 16384;
    bf16_t* swC2 = sw + 49152;
    bf16_t* swM1 = sw + 65536;
    bf16_t* swM2 = sw + 81920;

    int NB = (Nt + 1023) / 1024;   // blocks for the block-scan (<=128)

    k_prep<<<384, 256, 0, stream>>>(W_in, W_ctx1, W_ctx2, W_m1, W_m2, sw);
    // CSR build
    k_zero<<<(Nt + 255) / 256, 256, 0, stream>>>(start, Nt);
    k_hist<<<(E + 255) / 256, 256, 0, stream>>>(wi, start, E);
    k_scan_block<<<NB, 256, 0, stream>>>(start, bsum, Nt);
    k_scan_top<<<1, 128, 0, stream>>>(bsum, NB);
    k_scan_add<<<(Nt + 255) / 256, 256, 0, stream>>>(start, cursor, bsum, Nt);
    k_bucket<<<(E + 255) / 256, 256, 0, stream>>>(wi, cursor, elist, E);
    // main pipeline
    k_gemm_in<<<(Nt + 63) / 64, 256, 0, stream>>>(tfeat, swIn, tf, Nt);
    k_edge<<<(E + 63) / 64, 256, 0, stream>>>(cfeat, cpose, tpose, hi, wi,
                                              W_rp, b_rp, g_ctx, be_ctx,
                                              swC1, swC2, ctx, E);
    k_out<<<(Nt + 63) / 64, 256, 0, stream>>>(tf, tfeat, start, cursor, elist, ctx,
                                              g_n, be_n, g_m1, be_m1,
                                              g_m2, be_m2, swM1, swM2, outp, Nt);
}

// Round 4
// 647.932 us; speedup vs baseline: 1.0278x; 1.0278x over previous
//
#include <hip/hip_runtime.h>

typedef __bf16 bf16_t;
typedef bf16_t bf16x4 __attribute__((ext_vector_type(4)));
typedef bf16_t bf16x8 __attribute__((ext_vector_type(8)));
typedef float floatx4 __attribute__((ext_vector_type(4)));
typedef float floatx16 __attribute__((ext_vector_type(16)));

#define EPSF 1e-5f
#define DEV static __device__ __forceinline__

// ---------------------------------------------------------------------------
// K0: swizzle weights into MFMA B-fragment order (bf16).
// 16-wide (16x16x32): sw16[((t*4+s)*64+l)*8+j] = W[(s*32+(l>>4)*8+j)*128 + t*16+(l&15)]
// 32-wide (32x32x16): sw32[((t*nK+s)*64+l)*8+j] = W[(s*16+(l>>5)*8+j)*128 + t*32+(l&31)]
// Ranges (bf16 elems): swIn16@0, swM1_16@16384, swM2_16@32768,
//                      swC1_32@49152(32768), swC2_32@81920(16384). Total 98304.
// ---------------------------------------------------------------------------
__global__ __launch_bounds__(256) void k_prep(
    const float* __restrict__ W_in, const float* __restrict__ W_m1,
    const float* __restrict__ W_m2, const float* __restrict__ W_ctx1,
    const float* __restrict__ W_ctx2, bf16_t* __restrict__ sw)
{
    int idx = blockIdx.x * 256 + threadIdx.x;   // grid exactly 98304
    int j = (idx & 7), l = (idx >> 3) & 63;
    float v;
    if (idx < 49152) {
        // 16-wide: W_in / W_m1 / W_m2
        const float* W; int local;
        if (idx < 16384)      { W = W_in; local = idx; }
        else if (idx < 32768) { W = W_m1; local = idx - 16384; }
        else                  { W = W_m2; local = idx - 32768; }
        int rest = local >> 9;
        int s = rest & 3, t = rest >> 2;
        int k = s * 32 + (l >> 4) * 8 + j;
        int n = t * 16 + (l & 15);
        v = W[k * 128 + n];
    } else if (idx < 81920) {
        int local = idx - 49152;
        int rest = local >> 9;         // [0,64)
        int s = rest & 15, t = rest >> 4;
        int k = s * 16 + (l >> 5) * 8 + j;
        int n = t * 32 + (l & 31);
        v = W_ctx1[k * 128 + n];
    } else {
        int local = idx - 81920;
        int rest = local >> 9;         // [0,32)
        int s = rest & 7, t = rest >> 3;
        int k = s * 16 + (l >> 5) * 8 + j;
        int n = t * 32 + (l & 31);
        v = W_ctx2[k * 128 + n];
    }
    sw[idx] = (bf16_t)v;
}

// ---------------------------------------------------------------------------
// CSR construction
// ---------------------------------------------------------------------------
__global__ void k_zero(int* __restrict__ p, int n) {
    int i = blockIdx.x * 256 + threadIdx.x;
    if (i < n) p[i] = 0;
}

__global__ void k_hist(const int* __restrict__ wi, int* __restrict__ deg, int E) {
    int i = blockIdx.x * 256 + threadIdx.x;
    if (i < E) atomicAdd(&deg[wi[i]], 1);
}

__global__ __launch_bounds__(256) void k_scan_block(int* __restrict__ a,
                                                    int* __restrict__ bsum, int n) {
    __shared__ int wsum[4];
    int tid = threadIdx.x, lane = tid & 63, wv = tid >> 6;
    int base = blockIdx.x * 1024 + tid * 4;
    int v[4];
#pragma unroll
    for (int i = 0; i < 4; ++i) v[i] = (base + i < n) ? a[base + i] : 0;
    int tsum = v[0] + v[1] + v[2] + v[3];
    int sc = tsum;
#pragma unroll
    for (int d = 1; d < 64; d <<= 1) {
        int o = __shfl_up(sc, d);
        if (lane >= d) sc += o;
    }
    if (lane == 63) wsum[wv] = sc;
    __syncthreads();
    int wadd = 0;
    for (int w = 0; w < wv; ++w) wadd += wsum[w];
    int run = sc - tsum + wadd;
#pragma unroll
    for (int i = 0; i < 4; ++i) {
        int t = v[i];
        if (base + i < n) a[base + i] = run;
        run += t;
    }
    if (tid == 255) bsum[blockIdx.x] = wadd + sc;
}

__global__ __launch_bounds__(128) void k_scan_top(int* __restrict__ bsum, int nb) {
    __shared__ int s[128];
    int tid = threadIdx.x;
    int v = (tid < nb) ? bsum[tid] : 0;
    s[tid] = v;
    __syncthreads();
    for (int d = 1; d < 128; d <<= 1) {
        int t = (tid >= d) ? s[tid - d] : 0;
        __syncthreads();
        s[tid] += t;
        __syncthreads();
    }
    if (tid < nb) bsum[tid] = s[tid] - v;
}

__global__ void k_scan_add(int* __restrict__ a, int* __restrict__ cursor,
                           const int* __restrict__ bsum, int n) {
    int i = blockIdx.x * 256 + threadIdx.x;
    if (i < n) { int v = a[i] + bsum[i >> 10]; a[i] = v; cursor[i] = v; }
}

// perm[e] = CSR slot of edge e (so ctx written at perm[e] is sorted by target row)
__global__ void k_bucket(const int* __restrict__ wi, int* __restrict__ cursor,
                         int* __restrict__ perm, int E) {
    int e = blockIdx.x * 256 + threadIdx.x;
    if (e < E) { int p = atomicAdd(&cursor[wi[e]], 1); perm[e] = p; }
}

// GroupNorm on 16x16 MFMA C-layout accumulators (k_out).
DEV void gn_rows(floatx4* acc, int lane, const float* __restrict__ gamma,
                 const float* __restrict__ beta, bool do_relu)
{
    int m = lane & 15;
    float s1[4] = {0.f,0.f,0.f,0.f}, s2[4] = {0.f,0.f,0.f,0.f};
#pragma unroll
    for (int t = 0; t < 8; ++t)
#pragma unroll
        for (int rr = 0; rr < 4; ++rr) { float v = acc[t][rr]; s1[rr] += v; s2[rr] += v*v; }
#pragma unroll
    for (int mask = 1; mask <= 8; mask <<= 1)
#pragma unroll
        for (int rr = 0; rr < 4; ++rr) {
            s1[rr] += __shfl_xor(s1[rr], mask);
            s2[rr] += __shfl_xor(s2[rr], mask);
        }
    float mean[4], inv[4];
#pragma unroll
    for (int rr = 0; rr < 4; ++rr) {
        mean[rr] = s1[rr] * (1.f/128.f);
        float var = s2[rr] * (1.f/128.f) - mean[rr]*mean[rr];
        inv[rr] = rsqrtf(var + EPSF);
    }
#pragma unroll
    for (int t = 0; t < 8; ++t) {
        int n = t*16 + m;
        float ga = gamma[n], be = beta[n];
#pragma unroll
        for (int rr = 0; rr < 4; ++rr) {
            float v = (acc[t][rr] - mean[rr]) * inv[rr] * ga + be;
            acc[t][rr] = do_relu ? fmaxf(v, 0.f) : v;
        }
    }
}

// ---------------------------------------------------------------------------
// K1: tf = target_feat @ W_in   (16x16x32 path, unchanged)
// ---------------------------------------------------------------------------
__global__ __launch_bounds__(256) void k_gemm_in(
    const float* __restrict__ tfeat, const bf16_t* __restrict__ swW,
    float* __restrict__ tf, int Nt)
{
    __shared__ alignas(16) bf16_t sA[4][2048];
    int tid = threadIdx.x, lane = tid & 63, wave = tid >> 6;

    int tb = (blockIdx.x * 4 + wave) * 16;
    int r = lane >> 2, cb = (lane & 3) * 32;
    int grow = tb + r;
    bool rv = grow < Nt;
    const float4* src = (const float4*)(tfeat + (size_t)(rv ? grow : 0) * 128 + cb);
#pragma unroll
    for (int i = 0; i < 8; ++i) {
        float4 v = rv ? src[i] : make_float4(0.f,0.f,0.f,0.f);
        int k = cb + 4*i;
        int s = k >> 5, q = (k >> 3) & 3, j = k & 7;
        bf16x4 pk = { (bf16_t)v.x, (bf16_t)v.y, (bf16_t)v.z, (bf16_t)v.w };
        *(bf16x4*)&sA[wave][(s*64 + q*16 + r)*8 + j] = pk;
    }
    __syncthreads();
    int m = lane & 15, g = lane >> 4;
    bf16x8 aF[4];
#pragma unroll
    for (int s = 0; s < 4; ++s) aF[s] = *(const bf16x8*)&sA[wave][(s*64 + lane)*8];
#pragma unroll
    for (int t = 0; t < 8; ++t) {
        floatx4 a = {0.f,0.f,0.f,0.f};
#pragma unroll
        for (int s = 0; s < 4; ++s) {
            bf16x8 bF = *(const bf16x8*)&swW[((t*4+s)*64 + lane)*8];
            a = __builtin_amdgcn_mfma_f32_16x16x32_bf16(aF[s], bF, a, 0, 0, 0);
        }
#pragma unroll
        for (int rr = 0; rr < 4; ++rr) {
            int row = tb + g*4 + rr;
            if (row < Nt) tf[(size_t)row*128 + t*16 + m] = a[rr];
        }
    }
}

// ---------------------------------------------------------------------------
// K2: per-edge MLP, 32x32x16 MFMA, 64 edges/wave, 2 waves/block.
// A staged row-major in LDS (stride 136 bf16 = pad 8) and reused for
// GEMM1 pass0 (cfeat), pass1 (relpose), h (pre/post GN), all in place.
// Output rows stored to ctx[perm[e]] (CSR order) -> k_out reads contiguous.
// ---------------------------------------------------------------------------
__global__ __launch_bounds__(128, 2) void k_edge(
    const float* __restrict__ cfeat, const float* __restrict__ cpose,
    const float* __restrict__ tpose, const int* __restrict__ hi,
    const int* __restrict__ wi, const float* __restrict__ W_rp,
    const float* __restrict__ b_rp, const float* __restrict__ g_ctx,
    const float* __restrict__ be_ctx, const bf16_t* __restrict__ swC1,
    const bf16_t* __restrict__ swC2, const int* __restrict__ perm,
    bf16_t* __restrict__ ctx, int E)
{
    __shared__ alignas(16) bf16_t sH[2][64 * 136];
    int tid = threadIdx.x, lane = tid & 63, wave = tid >> 6;
    bf16_t* H = sH[wave];
    int eb = (blockIdx.x * 2 + wave) * 64;

    int rg = lane >> 2;           // 0..15 (staging row group)
    int cb = (lane & 3) * 32;     // staging col quarter
    int m = lane & 31, half = lane >> 5;

    floatx16 acc0[4], acc1[4];
#pragma unroll
    for (int n = 0; n < 4; ++n)
#pragma unroll
        for (int i = 0; i < 16; ++i) { acc0[n][i] = 0.f; acc1[n][i] = 0.f; }

    for (int pass = 0; pass < 2; ++pass) {
        // stage 64 rows x 128 ch (bf16, row stride 136)
#pragma unroll
        for (int p = 0; p < 4; ++p) {
            int r = p * 16 + rg;
            int e = min(eb + r, E - 1);
            if (pass == 0) {
                int ci = hi[e];
                const float4* srcp = (const float4*)(cfeat + (size_t)ci * 128 + cb);
#pragma unroll
                for (int i = 0; i < 8; ++i) {
                    float4 v = srcp[i];
                    bf16x4 pk = { (bf16_t)v.x, (bf16_t)v.y, (bf16_t)v.z, (bf16_t)v.w };
                    *(bf16x4*)&H[r * 136 + cb + i * 4] = pk;
                }
            } else {
                int ci = hi[e], ti = wi[e];
                float4 cp = ((const float4*)cpose)[ci];
                float4 tp = ((const float4*)tpose)[ti];
                float d0 = cp.x - tp.x, d1 = cp.y - tp.y,
                      d2 = cp.z - tp.z, d3 = cp.w - tp.w;
#pragma unroll
                for (int i = 0; i < 8; ++i) {
                    int c = cb + i * 4;
                    float4 w0 = *(const float4*)(W_rp + c);
                    float4 w1 = *(const float4*)(W_rp + 128 + c);
                    float4 w2 = *(const float4*)(W_rp + 256 + c);
                    float4 w3 = *(const float4*)(W_rp + 384 + c);
                    float4 bb = *(const float4*)(b_rp + c);
                    float o0 = fmaxf(d0*w0.x + d1*w1.x + d2*w2.x + d3*w3.x + bb.x, 0.f);
                    float o1 = fmaxf(d0*w0.y + d1*w1.y + d2*w2.y + d3*w3.y + bb.y, 0.f);
                    float o2 = fmaxf(d0*w0.z + d1*w1.z + d2*w2.z + d3*w3.z + bb.z, 0.f);
                    float o3 = fmaxf(d0*w0.w + d1*w1.w + d2*w2.w + d3*w3.w + bb.w, 0.f);
                    bf16x4 pk = { (bf16_t)o0, (bf16_t)o1, (bf16_t)o2, (bf16_t)o3 };
                    *(bf16x4*)&H[r * 136 + c] = pk;
                }
            }
        }
        __syncthreads();
        // 8 k-steps of 16 against this K-half
#pragma unroll
        for (int s = 0; s < 8; ++s) {
            bf16x8 a0 = *(const bf16x8*)&H[m * 136 + s * 16 + half * 8];
            bf16x8 a1 = *(const bf16x8*)&H[(32 + m) * 136 + s * 16 + half * 8];
            int sg = pass * 8 + s;
#pragma unroll
            for (int n = 0; n < 4; ++n) {
                bf16x8 bF = *(const bf16x8*)&swC1[(size_t)((n * 16 + sg) * 64 + lane) * 8];
                acc0[n] = __builtin_amdgcn_mfma_f32_32x32x16_bf16(a0, bF, acc0[n], 0, 0, 0);
                acc1[n] = __builtin_amdgcn_mfma_f32_32x32x16_bf16(a1, bF, acc1[n], 0, 0, 0);
            }
        }
        __syncthreads();
    }

    // write pre-GN h to H (row-major bf16). C-layout: col=lane&31,
    // row=(reg&3)+8*(reg>>2)+4*half  [measured m74/m101]
#pragma unroll
    for (int n = 0; n < 4; ++n)
#pragma unroll
        for (int reg = 0; reg < 16; ++reg) {
            int rl = (reg & 3) + 8 * (reg >> 2) + 4 * half;
            int col = n * 32 + m;
            H[rl * 136 + col]        = (bf16_t)acc0[n][reg];
            H[(32 + rl) * 136 + col] = (bf16_t)acc1[n][reg];
        }
    __syncthreads();

    // GN + ReLU in place (4 lanes per row, 32 ch each)
    {
        float ga[32], be[32];
#pragma unroll
        for (int i = 0; i < 8; ++i) {
            float4 g4 = *(const float4*)(g_ctx + cb + i * 4);
            float4 b4 = *(const float4*)(be_ctx + cb + i * 4);
            ga[i*4+0] = g4.x; ga[i*4+1] = g4.y; ga[i*4+2] = g4.z; ga[i*4+3] = g4.w;
            be[i*4+0] = b4.x; be[i*4+1] = b4.y; be[i*4+2] = b4.z; be[i*4+3] = b4.w;
        }
#pragma unroll
        for (int p = 0; p < 4; ++p) {
            int r = p * 16 + rg;
            float v[32]; float s1 = 0.f, s2 = 0.f;
#pragma unroll
            for (int i = 0; i < 4; ++i) {
                bf16x8 h8 = *(const bf16x8*)&H[r * 136 + cb + i * 8];
#pragma unroll
                for (int j = 0; j < 8; ++j) {
                    float f = (float)h8[j];
                    v[i*8+j] = f; s1 += f; s2 += f * f;
                }
            }
            s1 += __shfl_xor(s1, 1); s2 += __shfl_xor(s2, 1);
            s1 += __shfl_xor(s1, 2); s2 += __shfl_xor(s2, 2);
            float mean = s1 * (1.f/128.f);
            float inv = rsqrtf(s2 * (1.f/128.f) - mean * mean + EPSF);
#pragma unroll
            for (int i = 0; i < 4; ++i) {
                bf16x8 h8;
#pragma unroll
                for (int j = 0; j < 8; ++j)
                    h8[j] = (bf16_t)fmaxf((v[i*8+j] - mean) * inv * ga[i*8+j] + be[i*8+j], 0.f);
                *(bf16x8*)&H[r * 136 + cb + i * 8] = h8;
            }
        }
    }
    __syncthreads();

    // GEMM2: o = h @ W_ctx2  (K=128, 8 k-steps)
    floatx16 o0[4], o1[4];
#pragma unroll
    for (int n = 0; n < 4; ++n)
#pragma unroll
        for (int i = 0; i < 16; ++i) { o0[n][i] = 0.f; o1[n][i] = 0.f; }
#pragma unroll
    for (int s = 0; s < 8; ++s) {
        bf16x8 a0 = *(const bf16x8*)&H[m * 136 + s * 16 + half * 8];
        bf16x8 a1 = *(const bf16x8*)&H[(32 + m) * 136 + s * 16 + half * 8];
#pragma unroll
        for (int n = 0; n < 4; ++n) {
            bf16x8 bF = *(const bf16x8*)&swC2[(size_t)((n * 8 + s) * 64 + lane) * 8];
            o0[n] = __builtin_amdgcn_mfma_f32_32x32x16_bf16(a0, bF, o0[n], 0, 0, 0);
            o1[n] = __builtin_amdgcn_mfma_f32_32x32x16_bf16(a1, bF, o1[n], 0, 0, 0);
        }
    }

    // store to ctx at CSR slot perm[e]; per (reg,n) instruction the 32 lanes of
    // each half write 32 consecutive bf16 (64 B coalesced segments)
#pragma unroll
    for (int reg = 0; reg < 16; ++reg) {
        int rl = (reg & 3) + 8 * (reg >> 2) + 4 * half;
        int e0 = eb + rl, e1 = eb + 32 + rl;
        if (e0 < E) {
            size_t g0 = (size_t)perm[e0] * 128;
#pragma unroll
            for (int n = 0; n < 4; ++n) ctx[g0 + n * 32 + m] = (bf16_t)o0[n][reg];
        }
        if (e1 < E) {
            size_t g1 = (size_t)perm[e1] * 128;
#pragma unroll
            for (int n = 0; n < 4; ++n) ctx[g1 + n * 32 + m] = (bf16_t)o1[n][reg];
        }
    }
}

// ---------------------------------------------------------------------------
// K3: per target row: tf += sum(ctx[start..end) contiguous); then
// out = relu(GN(relu(GN(relu(GN(tf)) @ W_m1)) @ W_m2) + identity)
// ---------------------------------------------------------------------------
__global__ __launch_bounds__(256) void k_out(
    const float* __restrict__ tf, const float* __restrict__ identity,
    const int* __restrict__ start, const int* __restrict__ cend,
    const bf16_t* __restrict__ ctx,
    const float* __restrict__ g_n, const float* __restrict__ be_n,
    const float* __restrict__ g_m1, const float* __restrict__ be_m1,
    const float* __restrict__ g_m2, const float* __restrict__ be_m2,
    const bf16_t* __restrict__ swM1, const bf16_t* __restrict__ swM2,
    float* __restrict__ out, int Nt)
{
    __shared__ alignas(16) bf16_t sA[4][2048];
    int tid = threadIdx.x, lane = tid & 63, wave = tid >> 6;

    int tb = (blockIdx.x*4 + wave)*16;
    int r = lane >> 2, cb = (lane & 3)*32;
    int grow = tb + r;
    bool rv = grow < Nt;
    const float4* src = (const float4*)(tf + (size_t)(rv ? grow : 0)*128 + cb);
    float vals[32];
#pragma unroll
    for (int i = 0; i < 8; ++i) {
        float4 v = rv ? src[i] : make_float4(0.f,0.f,0.f,0.f);
        vals[4*i+0]=v.x; vals[4*i+1]=v.y; vals[4*i+2]=v.z; vals[4*i+3]=v.w;
    }
    // contiguous CSR range of ctx rows (sorted by target)
    int s0 = rv ? start[grow] : 0;
    int s1 = rv ? cend[grow] : 0;
    for (int p = s0; p < s1; ++p) {
        const bf16x8* cp = (const bf16x8*)(ctx + (size_t)p*128 + cb);
#pragma unroll
        for (int i = 0; i < 4; ++i) {
            bf16x8 c8 = cp[i];
#pragma unroll
            for (int j = 0; j < 8; ++j) vals[8*i+j] += (float)c8[j];
        }
    }
    float ls = 0.f, lq = 0.f;
#pragma unroll
    for (int i = 0; i < 32; ++i) { ls += vals[i]; lq += vals[i]*vals[i]; }
    ls += __shfl_xor(ls,1); lq += __shfl_xor(lq,1);
    ls += __shfl_xor(ls,2); lq += __shfl_xor(lq,2);
    float mean = ls*(1.f/128.f);
    float inv = rsqrtf(lq*(1.f/128.f) - mean*mean + EPSF);
#pragma unroll
    for (int i = 0; i < 8; ++i) {
        int c = cb + 4*i;
        float4 ga = *(const float4*)(g_n + c);
        float4 be = *(const float4*)(be_n + c);
        float o0 = fmaxf((vals[4*i+0]-mean)*inv*ga.x + be.x, 0.f);
        float o1 = fmaxf((vals[4*i+1]-mean)*inv*ga.y + be.y, 0.f);
        float o2 = fmaxf((vals[4*i+2]-mean)*inv*ga.z + be.z, 0.f);
        float o3 = fmaxf((vals[4*i+3]-mean)*inv*ga.w + be.w, 0.f);
        int s = c >> 5, q = (c >> 3) & 3, j = c & 7;
        bf16x4 pk = { (bf16_t)o0, (bf16_t)o1, (bf16_t)o2, (bf16_t)o3 };
        *(bf16x4*)&sA[wave][(s*64 + q*16 + r)*8 + j] = pk;
    }
    __syncthreads();
    int m = lane & 15, g = lane >> 4;
    bf16x8 aF[4];
#pragma unroll
    for (int s = 0; s < 4; ++s) aF[s] = *(const bf16x8*)&sA[wave][(s*64 + lane)*8];
    floatx4 acc[8];
#pragma unroll
    for (int t = 0; t < 8; ++t) {
        floatx4 a = {0.f,0.f,0.f,0.f};
#pragma unroll
        for (int s = 0; s < 4; ++s) {
            bf16x8 bF = *(const bf16x8*)&swM1[((t*4+s)*64 + lane)*8];
            a = __builtin_amdgcn_mfma_f32_16x16x32_bf16(aF[s], bF, a, 0, 0, 0);
        }
        acc[t] = a;
    }
    gn_rows(acc, lane, g_m1, be_m1, true);
    __syncthreads();
#pragma unroll
    for (int t = 0; t < 8; ++t) {
        int n = t*16 + m;
        int s = n >> 5, q = (n >> 3) & 3, j = n & 7;
#pragma unroll
        for (int rr = 0; rr < 4; ++rr)
            sA[wave][(s*64 + q*16 + (g*4+rr))*8 + j] = (bf16_t)acc[t][rr];
    }
    __syncthreads();
#pragma unroll
    for (int s = 0; s < 4; ++s) aF[s] = *(const bf16x8*)&sA[wave][(s*64 + lane)*8];
#pragma unroll
    for (int t = 0; t < 8; ++t) {
        floatx4 a = {0.f,0.f,0.f,0.f};
#pragma unroll
        for (int s = 0; s < 4; ++s) {
            bf16x8 bF = *(const bf16x8*)&swM2[((t*4+s)*64 + lane)*8];
            a = __builtin_amdgcn_mfma_f32_16x16x32_bf16(aF[s], bF, a, 0, 0, 0);
        }
        acc[t] = a;
    }
    gn_rows(acc, lane, g_m2, be_m2, false);
#pragma unroll
    for (int t = 0; t < 8; ++t) {
        int n = t*16 + m;
#pragma unroll
        for (int rr = 0; rr < 4; ++rr) {
            int row = tb + g*4 + rr;
            if (row < Nt) {
                float v = acc[t][rr] + identity[(size_t)row*128 + n];
                out[(size_t)row*128 + n] = fmaxf(v, 0.f);
            }
        }
    }
}

// ---------------------------------------------------------------------------
extern "C" void kernel_launch(void* const* d_in, const int* in_sizes, int n_in,
                              void* d_out, int out_size, void* d_ws, size_t ws_size,
                              hipStream_t stream)
{
    const float* cfeat  = (const float*)d_in[0];
    const float* tfeat  = (const float*)d_in[1];
    const float* cpose  = (const float*)d_in[2];
    const float* tpose  = (const float*)d_in[3];
    const int*   hi     = (const int*)d_in[4];
    const int*   wi     = (const int*)d_in[5];
    const float* W_in   = (const float*)d_in[6];
    const float* W_rp   = (const float*)d_in[7];
    const float* b_rp   = (const float*)d_in[8];
    const float* W_ctx1 = (const float*)d_in[9];
    const float* g_ctx  = (const float*)d_in[10];
    const float* be_ctx = (const float*)d_in[11];
    const float* W_ctx2 = (const float*)d_in[12];
    const float* g_n    = (const float*)d_in[13];
    const float* be_n   = (const float*)d_in[14];
    const float* W_m1   = (const float*)d_in[15];
    const float* g_m1   = (const float*)d_in[16];
    const float* be_m1  = (const float*)d_in[17];
    const float* W_m2   = (const float*)d_in[18];
    const float* g_m2   = (const float*)d_in[19];
    const float* be_m2  = (const float*)d_in[20];

    int Nt = in_sizes[1] / 128;
    int E  = in_sizes[4];
    float* outp = (float*)d_out;

    char* w = (char*)d_ws;
    size_t off = 0;
    auto alloc = [&](size_t bytes) { char* p = w + off;
        off = (off + bytes + 255) & ~(size_t)255; return p; };
    float*  tf     = (float*) alloc((size_t)Nt * 128 * sizeof(float));
    bf16_t* sw     = (bf16_t*)alloc(98304 * sizeof(bf16_t));
    bf16_t* ctx    = (bf16_t*)alloc((size_t)E * 128 * sizeof(bf16_t));
    int*    start  = (int*)   alloc((size_t)Nt * sizeof(int));
    int*    cursor = (int*)   alloc((size_t)Nt * sizeof(int));
    int*    perm   = (int*)   alloc((size_t)E * sizeof(int));
    int*    bsum   = (int*)   alloc(128 * sizeof(int));

    bf16_t* swIn = sw;
    bf16_t* swM1 = sw + 16384;
    bf16_t* swM2 = sw + 32768;
    bf16_t* swC1 = sw + 49152;
    bf16_t* swC2 = sw + 81920;

    int NB = (Nt + 1023) / 1024;

    k_prep<<<384, 256, 0, stream>>>(W_in, W_m1, W_m2, W_ctx1, W_ctx2, sw);
    // CSR build
    k_zero<<<(Nt + 255) / 256, 256, 0, stream>>>(start, Nt);
    k_hist<<<(E + 255) / 256, 256, 0, stream>>>(wi, start, E);
    k_scan_block<<<NB, 256, 0, stream>>>(start, bsum, Nt);
    k_scan_top<<<1, 128, 0, stream>>>(bsum, NB);
    k_scan_add<<<(Nt + 255) / 256, 256, 0, stream>>>(start, cursor, bsum, Nt);
    k_bucket<<<(E + 255) / 256, 256, 0, stream>>>(wi, cursor, perm, E);
    // main pipeline
    k_gemm_in<<<(Nt + 63) / 64, 256, 0, stream>>>(tfeat, swIn, tf, Nt);
    k_edge<<<(E + 127) / 128, 128, 0, stream>>>(cfeat, cpose, tpose, hi, wi,
                                                W_rp, b_rp, g_ctx, be_ctx,
                                                swC1, swC2, perm, ctx, E);
    k_out<<<(Nt + 63) / 64, 256, 0, stream>>>(tf, tfeat, start, cursor, ctx,
                                              g_n, be_n, g_m1, be_m1,
                                              g_m2, be_m2, swM1, swM2, outp, Nt);
}

// Round 5
// 642.202 us; speedup vs baseline: 1.0369x; 1.0089x over previous
//
#include <hip/hip_runtime.h>

typedef __bf16 bf16_t;
typedef bf16_t bf16x4 __attribute__((ext_vector_type(4)));
typedef bf16_t bf16x8 __attribute__((ext_vector_type(8)));
typedef float floatx4 __attribute__((ext_vector_type(4)));
typedef float floatx16 __attribute__((ext_vector_type(16)));

#define EPSF 1e-5f
#define DEV static __device__ __forceinline__

// ---------------------------------------------------------------------------
// K0: swizzle weights into MFMA B-fragment order (bf16).
// 16-wide (16x16x32): sw16[((t*4+s)*64+l)*8+j] = W[(s*32+(l>>4)*8+j)*128 + t*16+(l&15)]
// 32-wide (32x32x16): sw32[((t*nK+s)*64+l)*8+j] = W[(s*16+(l>>5)*8+j)*128 + t*32+(l&31)]
// Ranges (bf16 elems): swIn16@0, swM1_16@16384, swM2_16@32768,
//                      swC1_32@49152(32768), swC2_32@81920(16384). Total 98304.
// ---------------------------------------------------------------------------
__global__ __launch_bounds__(256) void k_prep(
    const float* __restrict__ W_in, const float* __restrict__ W_m1,
    const float* __restrict__ W_m2, const float* __restrict__ W_ctx1,
    const float* __restrict__ W_ctx2, bf16_t* __restrict__ sw)
{
    int idx = blockIdx.x * 256 + threadIdx.x;   // grid exactly 98304
    int j = (idx & 7), l = (idx >> 3) & 63;
    float v;
    if (idx < 49152) {
        const float* W; int local;
        if (idx < 16384)      { W = W_in; local = idx; }
        else if (idx < 32768) { W = W_m1; local = idx - 16384; }
        else                  { W = W_m2; local = idx - 32768; }
        int rest = local >> 9;
        int s = rest & 3, t = rest >> 2;
        int k = s * 32 + (l >> 4) * 8 + j;
        int n = t * 16 + (l & 15);
        v = W[k * 128 + n];
    } else if (idx < 81920) {
        int local = idx - 49152;
        int rest = local >> 9;         // [0,64)
        int s = rest & 15, t = rest >> 4;
        int k = s * 16 + (l >> 5) * 8 + j;
        int n = t * 32 + (l & 31);
        v = W_ctx1[k * 128 + n];
    } else {
        int local = idx - 81920;
        int rest = local >> 9;         // [0,32)
        int s = rest & 7, t = rest >> 3;
        int k = s * 16 + (l >> 5) * 8 + j;
        int n = t * 32 + (l & 31);
        v = W_ctx2[k * 128 + n];
    }
    sw[idx] = (bf16_t)v;
}

// ---------------------------------------------------------------------------
// CSR construction
// ---------------------------------------------------------------------------
__global__ void k_zero(int* __restrict__ p, int n) {
    int i = blockIdx.x * 256 + threadIdx.x;
    if (i < n) p[i] = 0;
}

__global__ void k_hist(const int* __restrict__ wi, int* __restrict__ deg, int E) {
    int i = blockIdx.x * 256 + threadIdx.x;
    if (i < E) atomicAdd(&deg[wi[i]], 1);
}

__global__ __launch_bounds__(256) void k_scan_block(int* __restrict__ a,
                                                    int* __restrict__ bsum, int n) {
    __shared__ int wsum[4];
    int tid = threadIdx.x, lane = tid & 63, wv = tid >> 6;
    int base = blockIdx.x * 1024 + tid * 4;
    int v[4];
#pragma unroll
    for (int i = 0; i < 4; ++i) v[i] = (base + i < n) ? a[base + i] : 0;
    int tsum = v[0] + v[1] + v[2] + v[3];
    int sc = tsum;
#pragma unroll
    for (int d = 1; d < 64; d <<= 1) {
        int o = __shfl_up(sc, d);
        if (lane >= d) sc += o;
    }
    if (lane == 63) wsum[wv] = sc;
    __syncthreads();
    int wadd = 0;
    for (int w = 0; w < wv; ++w) wadd += wsum[w];
    int run = sc - tsum + wadd;
#pragma unroll
    for (int i = 0; i < 4; ++i) {
        int t = v[i];
        if (base + i < n) a[base + i] = run;
        run += t;
    }
    if (tid == 255) bsum[blockIdx.x] = wadd + sc;
}

__global__ __launch_bounds__(128) void k_scan_top(int* __restrict__ bsum, int nb) {
    __shared__ int s[128];
    int tid = threadIdx.x;
    int v = (tid < nb) ? bsum[tid] : 0;
    s[tid] = v;
    __syncthreads();
    for (int d = 1; d < 128; d <<= 1) {
        int t = (tid >= d) ? s[tid - d] : 0;
        __syncthreads();
        s[tid] += t;
        __syncthreads();
    }
    if (tid < nb) bsum[tid] = s[tid] - v;
}

__global__ void k_scan_add(int* __restrict__ a, int* __restrict__ cursor,
                           const int* __restrict__ bsum, int n) {
    int i = blockIdx.x * 256 + threadIdx.x;
    if (i < n) { int v = a[i] + bsum[i >> 10]; a[i] = v; cursor[i] = v; }
}

// perm[e] = CSR slot of edge e (ctx written at perm[e] is sorted by target row)
__global__ void k_bucket(const int* __restrict__ wi, int* __restrict__ cursor,
                         int* __restrict__ perm, int E) {
    int e = blockIdx.x * 256 + threadIdx.x;
    if (e < E) { int p = atomicAdd(&cursor[wi[e]], 1); perm[e] = p; }
}

// GroupNorm on 16x16 MFMA C-layout accumulators (k_out).
DEV void gn_rows(floatx4* acc, int lane, const float* __restrict__ gamma,
                 const float* __restrict__ beta, bool do_relu)
{
    int m = lane & 15;
    float s1[4] = {0.f,0.f,0.f,0.f}, s2[4] = {0.f,0.f,0.f,0.f};
#pragma unroll
    for (int t = 0; t < 8; ++t)
#pragma unroll
        for (int rr = 0; rr < 4; ++rr) { float v = acc[t][rr]; s1[rr] += v; s2[rr] += v*v; }
#pragma unroll
    for (int mask = 1; mask <= 8; mask <<= 1)
#pragma unroll
        for (int rr = 0; rr < 4; ++rr) {
            s1[rr] += __shfl_xor(s1[rr], mask);
            s2[rr] += __shfl_xor(s2[rr], mask);
        }
    float mean[4], inv[4];
#pragma unroll
    for (int rr = 0; rr < 4; ++rr) {
        mean[rr] = s1[rr] * (1.f/128.f);
        float var = s2[rr] * (1.f/128.f) - mean[rr]*mean[rr];
        inv[rr] = rsqrtf(var + EPSF);
    }
#pragma unroll
    for (int t = 0; t < 8; ++t) {
        int n = t*16 + m;
        float ga = gamma[n], be = beta[n];
#pragma unroll
        for (int rr = 0; rr < 4; ++rr) {
            float v = (acc[t][rr] - mean[rr]) * inv[rr] * ga + be;
            acc[t][rr] = do_relu ? fmaxf(v, 0.f) : v;
        }
    }
}

// ---------------------------------------------------------------------------
// K1: tf = target_feat @ W_in   (16x16x32 path)
// ---------------------------------------------------------------------------
__global__ __launch_bounds__(256) void k_gemm_in(
    const float* __restrict__ tfeat, const bf16_t* __restrict__ swW,
    float* __restrict__ tf, int Nt)
{
    __shared__ alignas(16) bf16_t sA[4][2048];
    int tid = threadIdx.x, lane = tid & 63, wave = tid >> 6;

    int tb = (blockIdx.x * 4 + wave) * 16;
    int r = lane >> 2, cb = (lane & 3) * 32;
    int grow = tb + r;
    bool rv = grow < Nt;
    const float4* src = (const float4*)(tfeat + (size_t)(rv ? grow : 0) * 128 + cb);
#pragma unroll
    for (int i = 0; i < 8; ++i) {
        float4 v = rv ? src[i] : make_float4(0.f,0.f,0.f,0.f);
        int k = cb + 4*i;
        int s = k >> 5, q = (k >> 3) & 3, j = k & 7;
        bf16x4 pk = { (bf16_t)v.x, (bf16_t)v.y, (bf16_t)v.z, (bf16_t)v.w };
        *(bf16x4*)&sA[wave][(s*64 + q*16 + r)*8 + j] = pk;
    }
    __syncthreads();
    int m = lane & 15, g = lane >> 4;
    bf16x8 aF[4];
#pragma unroll
    for (int s = 0; s < 4; ++s) aF[s] = *(const bf16x8*)&sA[wave][(s*64 + lane)*8];
#pragma unroll
    for (int t = 0; t < 8; ++t) {
        floatx4 a = {0.f,0.f,0.f,0.f};
#pragma unroll
        for (int s = 0; s < 4; ++s) {
            bf16x8 bF = *(const bf16x8*)&swW[((t*4+s)*64 + lane)*8];
            a = __builtin_amdgcn_mfma_f32_16x16x32_bf16(aF[s], bF, a, 0, 0, 0);
        }
#pragma unroll
        for (int rr = 0; rr < 4; ++rr) {
            int row = tb + g*4 + rr;
            if (row < Nt) tf[(size_t)row*128 + t*16 + m] = a[rr];
        }
    }
}

// ---------------------------------------------------------------------------
// K2: per-edge MLP. ONE wave per block, 32 edges/wave, 8.7 KB LDS.
// 16 blocks/CU (HW cap) = 4 waves/SIMD, fully independent (barriers within a
// single-wave block degrade to waitcnt). 32x32x16 MFMA.
// Output rows stored (via LDS bounce, 16 B stores) to ctx[perm[e]].
// ---------------------------------------------------------------------------
__global__ __launch_bounds__(64, 4) void k_edge(
    const float* __restrict__ cfeat, const float* __restrict__ cpose,
    const float* __restrict__ tpose, const int* __restrict__ hi,
    const int* __restrict__ wi, const float* __restrict__ W_rp,
    const float* __restrict__ b_rp, const float* __restrict__ g_ctx,
    const float* __restrict__ be_ctx, const bf16_t* __restrict__ swC1,
    const bf16_t* __restrict__ swC2, const int* __restrict__ perm,
    bf16_t* __restrict__ ctx, int E)
{
    __shared__ alignas(16) bf16_t H[32 * 136];
    int lane = threadIdx.x;
    int eb = blockIdx.x * 32;
    int m = lane & 31, half = lane >> 5;
    int r2 = lane >> 1, cq = (lane & 1) * 64;   // staging: 2 lanes/row, 64 ch each

    int e2 = min(eb + r2, E - 1);
    int ci2 = hi[e2], ti2 = wi[e2];

    floatx16 acc[4];
#pragma unroll
    for (int n = 0; n < 4; ++n)
#pragma unroll
        for (int i = 0; i < 16; ++i) acc[n][i] = 0.f;

    // ---- pass 0: stage gathered cfeat rows (k = 0..127) ----
    {
        const float4* srcp = (const float4*)(cfeat + (size_t)ci2 * 128 + cq);
#pragma unroll
        for (int i = 0; i < 16; ++i) {
            float4 v = srcp[i];
            bf16x4 pk = { (bf16_t)v.x, (bf16_t)v.y, (bf16_t)v.z, (bf16_t)v.w };
            *(bf16x4*)&H[r2 * 136 + cq + i * 4] = pk;
        }
    }
    __syncthreads();
#pragma unroll
    for (int s = 0; s < 8; ++s) {
        bf16x8 a = *(const bf16x8*)&H[m * 136 + s * 16 + half * 8];
#pragma unroll
        for (int n = 0; n < 4; ++n) {
            bf16x8 bF = *(const bf16x8*)&swC1[(size_t)((n * 16 + s) * 64 + lane) * 8];
            acc[n] = __builtin_amdgcn_mfma_f32_32x32x16_bf16(a, bF, acc[n], 0, 0, 0);
        }
    }
    __syncthreads();

    // ---- pass 1: relpose features (k = 128..255) ----
    {
        float4 cp = ((const float4*)cpose)[ci2];
        float4 tp = ((const float4*)tpose)[ti2];
        float d0 = cp.x - tp.x, d1 = cp.y - tp.y, d2 = cp.z - tp.z, d3 = cp.w - tp.w;
#pragma unroll
        for (int i = 0; i < 16; ++i) {
            int c = cq + i * 4;
            float4 w0 = *(const float4*)(W_rp + c);
            float4 w1 = *(const float4*)(W_rp + 128 + c);
            float4 w2 = *(const float4*)(W_rp + 256 + c);
            float4 w3 = *(const float4*)(W_rp + 384 + c);
            float4 bb = *(const float4*)(b_rp + c);
            float o0 = fmaxf(d0*w0.x + d1*w1.x + d2*w2.x + d3*w3.x + bb.x, 0.f);
            float o1 = fmaxf(d0*w0.y + d1*w1.y + d2*w2.y + d3*w3.y + bb.y, 0.f);
            float o2 = fmaxf(d0*w0.z + d1*w1.z + d2*w2.z + d3*w3.z + bb.z, 0.f);
            float o3 = fmaxf(d0*w0.w + d1*w1.w + d2*w2.w + d3*w3.w + bb.w, 0.f);
            bf16x4 pk = { (bf16_t)o0, (bf16_t)o1, (bf16_t)o2, (bf16_t)o3 };
            *(bf16x4*)&H[r2 * 136 + c] = pk;
        }
    }
    __syncthreads();
#pragma unroll
    for (int s = 0; s < 8; ++s) {
        bf16x8 a = *(const bf16x8*)&H[m * 136 + s * 16 + half * 8];
#pragma unroll
        for (int n = 0; n < 4; ++n) {
            bf16x8 bF = *(const bf16x8*)&swC1[(size_t)((n * 16 + 8 + s) * 64 + lane) * 8];
            acc[n] = __builtin_amdgcn_mfma_f32_32x32x16_bf16(a, bF, acc[n], 0, 0, 0);
        }
    }
    __syncthreads();

    // ---- write pre-GN h to H (row-major). C-layout: col=n*32+m,
    // row=(reg&3)+8*(reg>>2)+4*half  [measured m74/m101] ----
#pragma unroll
    for (int n = 0; n < 4; ++n)
#pragma unroll
        for (int reg = 0; reg < 16; ++reg) {
            int rl = (reg & 3) + 8 * (reg >> 2) + 4 * half;
            H[rl * 136 + n * 32 + m] = (bf16_t)acc[n][reg];
        }
    __syncthreads();

    // ---- GN + ReLU in place (2 lanes/row, 64 ch each, two-pass) ----
    {
        float s1 = 0.f, s2 = 0.f;
#pragma unroll
        for (int i = 0; i < 8; ++i) {
            bf16x8 h8 = *(const bf16x8*)&H[r2 * 136 + cq + i * 8];
#pragma unroll
            for (int j = 0; j < 8; ++j) { float f = (float)h8[j]; s1 += f; s2 += f * f; }
        }
        s1 += __shfl_xor(s1, 1);
        s2 += __shfl_xor(s2, 1);
        float mean = s1 * (1.f/128.f);
        float inv = rsqrtf(s2 * (1.f/128.f) - mean * mean + EPSF);
#pragma unroll
        for (int i = 0; i < 8; ++i) {
            int c = cq + i * 8;
            bf16x8 h8 = *(const bf16x8*)&H[r2 * 136 + c];
            float4 g0 = *(const float4*)(g_ctx + c);
            float4 g1 = *(const float4*)(g_ctx + c + 4);
            float4 b0 = *(const float4*)(be_ctx + c);
            float4 b1 = *(const float4*)(be_ctx + c + 4);
            float ga[8] = {g0.x,g0.y,g0.z,g0.w,g1.x,g1.y,g1.z,g1.w};
            float be[8] = {b0.x,b0.y,b0.z,b0.w,b1.x,b1.y,b1.z,b1.w};
            bf16x8 o8;
#pragma unroll
            for (int j = 0; j < 8; ++j)
                o8[j] = (bf16_t)fmaxf(((float)h8[j] - mean) * inv * ga[j] + be[j], 0.f);
            *(bf16x8*)&H[r2 * 136 + c] = o8;
        }
    }
    __syncthreads();

    // ---- GEMM2: o = h @ W_ctx2 (K=128) ----
    floatx16 o[4];
#pragma unroll
    for (int n = 0; n < 4; ++n)
#pragma unroll
        for (int i = 0; i < 16; ++i) o[n][i] = 0.f;
#pragma unroll
    for (int s = 0; s < 8; ++s) {
        bf16x8 a = *(const bf16x8*)&H[m * 136 + s * 16 + half * 8];
#pragma unroll
        for (int n = 0; n < 4; ++n) {
            bf16x8 bF = *(const bf16x8*)&swC2[(size_t)((n * 8 + s) * 64 + lane) * 8];
            o[n] = __builtin_amdgcn_mfma_f32_32x32x16_bf16(a, bF, o[n], 0, 0, 0);
        }
    }
    __syncthreads();

    // ---- bounce o through H, then 16 B coalesced stores to ctx[perm[e]] ----
#pragma unroll
    for (int n = 0; n < 4; ++n)
#pragma unroll
        for (int reg = 0; reg < 16; ++reg) {
            int rl = (reg & 3) + 8 * (reg >> 2) + 4 * half;
            H[rl * 136 + n * 32 + m] = (bf16_t)o[n][reg];
        }
    __syncthreads();
    if (eb + r2 < E) {
        int p = perm[eb + r2];
        const uint4* hsrc = (const uint4*)&H[r2 * 136 + cq];
        uint4* dst = (uint4*)(ctx + (size_t)p * 128 + cq);
#pragma unroll
        for (int i = 0; i < 8; ++i) dst[i] = hsrc[i];
    }
}

// ---------------------------------------------------------------------------
// K3: per target row: tf += sum(ctx[start..end) contiguous, unrolled x2); then
// out = relu(GN(relu(GN(relu(GN(tf)) @ W_m1)) @ W_m2) + identity)
// ---------------------------------------------------------------------------
__global__ __launch_bounds__(256) void k_out(
    const float* __restrict__ tf, const float* __restrict__ identity,
    const int* __restrict__ start, const int* __restrict__ cend,
    const bf16_t* __restrict__ ctx,
    const float* __restrict__ g_n, const float* __restrict__ be_n,
    const float* __restrict__ g_m1, const float* __restrict__ be_m1,
    const float* __restrict__ g_m2, const float* __restrict__ be_m2,
    const bf16_t* __restrict__ swM1, const bf16_t* __restrict__ swM2,
    float* __restrict__ out, int Nt)
{
    __shared__ alignas(16) bf16_t sA[4][2048];
    int tid = threadIdx.x, lane = tid & 63, wave = tid >> 6;

    int tb = (blockIdx.x*4 + wave)*16;
    int r = lane >> 2, cb = (lane & 3)*32;
    int grow = tb + r;
    bool rv = grow < Nt;
    const float4* src = (const float4*)(tf + (size_t)(rv ? grow : 0)*128 + cb);
    float vals[32];
#pragma unroll
    for (int i = 0; i < 8; ++i) {
        float4 v = rv ? src[i] : make_float4(0.f,0.f,0.f,0.f);
        vals[4*i+0]=v.x; vals[4*i+1]=v.y; vals[4*i+2]=v.z; vals[4*i+3]=v.w;
    }
    // contiguous CSR range of ctx rows, unrolled x2 with hoisted loads
    int s0 = rv ? start[grow] : 0;
    int s1 = rv ? cend[grow] : 0;
    int p = s0;
    for (; p + 1 < s1; p += 2) {
        const bf16x8* cp0 = (const bf16x8*)(ctx + (size_t)p*128 + cb);
        const bf16x8* cp1 = (const bf16x8*)(ctx + (size_t)(p+1)*128 + cb);
        bf16x8 r0[4], r1[4];
#pragma unroll
        for (int i = 0; i < 4; ++i) { r0[i] = cp0[i]; r1[i] = cp1[i]; }
#pragma unroll
        for (int i = 0; i < 4; ++i)
#pragma unroll
            for (int j = 0; j < 8; ++j)
                vals[8*i+j] += (float)r0[i][j] + (float)r1[i][j];
    }
    if (p < s1) {
        const bf16x8* cp0 = (const bf16x8*)(ctx + (size_t)p*128 + cb);
#pragma unroll
        for (int i = 0; i < 4; ++i) {
            bf16x8 c8 = cp0[i];
#pragma unroll
            for (int j = 0; j < 8; ++j) vals[8*i+j] += (float)c8[j];
        }
    }
    float ls = 0.f, lq = 0.f;
#pragma unroll
    for (int i = 0; i < 32; ++i) { ls += vals[i]; lq += vals[i]*vals[i]; }
    ls += __shfl_xor(ls,1); lq += __shfl_xor(lq,1);
    ls += __shfl_xor(ls,2); lq += __shfl_xor(lq,2);
    float mean = ls*(1.f/128.f);
    float inv = rsqrtf(lq*(1.f/128.f) - mean*mean + EPSF);
#pragma unroll
    for (int i = 0; i < 8; ++i) {
        int c = cb + 4*i;
        float4 ga = *(const float4*)(g_n + c);
        float4 be = *(const float4*)(be_n + c);
        float o0 = fmaxf((vals[4*i+0]-mean)*inv*ga.x + be.x, 0.f);
        float o1 = fmaxf((vals[4*i+1]-mean)*inv*ga.y + be.y, 0.f);
        float o2 = fmaxf((vals[4*i+2]-mean)*inv*ga.z + be.z, 0.f);
        float o3 = fmaxf((vals[4*i+3]-mean)*inv*ga.w + be.w, 0.f);
        int s = c >> 5, q = (c >> 3) & 3, j = c & 7;
        bf16x4 pk = { (bf16_t)o0, (bf16_t)o1, (bf16_t)o2, (bf16_t)o3 };
        *(bf16x4*)&sA[wave][(s*64 + q*16 + r)*8 + j] = pk;
    }
    __syncthreads();
    int m = lane & 15, g = lane >> 4;
    bf16x8 aF[4];
#pragma unroll
    for (int s = 0; s < 4; ++s) aF[s] = *(const bf16x8*)&sA[wave][(s*64 + lane)*8];
    floatx4 acc[8];
#pragma unroll
    for (int t = 0; t < 8; ++t) {
        floatx4 a = {0.f,0.f,0.f,0.f};
#pragma unroll
        for (int s = 0; s < 4; ++s) {
            bf16x8 bF = *(const bf16x8*)&swM1[((t*4+s)*64 + lane)*8];
            a = __builtin_amdgcn_mfma_f32_16x16x32_bf16(aF[s], bF, a, 0, 0, 0);
        }
        acc[t] = a;
    }
    gn_rows(acc, lane, g_m1, be_m1, true);
    __syncthreads();
#pragma unroll
    for (int t = 0; t < 8; ++t) {
        int n = t*16 + m;
        int s = n >> 5, q = (n >> 3) & 3, j = n & 7;
#pragma unroll
        for (int rr = 0; rr < 4; ++rr)
            sA[wave][(s*64 + q*16 + (g*4+rr))*8 + j] = (bf16_t)acc[t][rr];
    }
    __syncthreads();
#pragma unroll
    for (int s = 0; s < 4; ++s) aF[s] = *(const bf16x8*)&sA[wave][(s*64 + lane)*8];
#pragma unroll
    for (int t = 0; t < 8; ++t) {
        floatx4 a = {0.f,0.f,0.f,0.f};
#pragma unroll
        for (int s = 0; s < 4; ++s) {
            bf16x8 bF = *(const bf16x8*)&swM2[((t*4+s)*64 + lane)*8];
            a = __builtin_amdgcn_mfma_f32_16x16x32_bf16(aF[s], bF, a, 0, 0, 0);
        }
        acc[t] = a;
    }
    gn_rows(acc, lane, g_m2, be_m2, false);
#pragma unroll
    for (int t = 0; t < 8; ++t) {
        int n = t*16 + m;
#pragma unroll
        for (int rr = 0; rr < 4; ++rr) {
            int row = tb + g*4 + rr;
            if (row < Nt) {
                float v = acc[t][rr] + identity[(size_t)row*128 + n];
                out[(size_t)row*128 + n] = fmaxf(v, 0.f);
            }
        }
    }
}

// ---------------------------------------------------------------------------
extern "C" void kernel_launch(void* const* d_in, const int* in_sizes, int n_in,
                              void* d_out, int out_size, void* d_ws, size_t ws_size,
                              hipStream_t stream)
{
    const float* cfeat  = (const float*)d_in[0];
    const float* tfeat  = (const float*)d_in[1];
    const float* cpose  = (const float*)d_in[2];
    const float* tpose  = (const float*)d_in[3];
    const int*   hi     = (const int*)d_in[4];
    const int*   wi     = (const int*)d_in[5];
    const float* W_in   = (const float*)d_in[6];
    const float* W_rp   = (const float*)d_in[7];
    const float* b_rp   = (const float*)d_in[8];
    const float* W_ctx1 = (const float*)d_in[9];
    const float* g_ctx  = (const float*)d_in[10];
    const float* be_ctx = (const float*)d_in[11];
    const float* W_ctx2 = (const float*)d_in[12];
    const float* g_n    = (const float*)d_in[13];
    const float* be_n   = (const float*)d_in[14];
    const float* W_m1   = (const float*)d_in[15];
    const float* g_m1   = (const float*)d_in[16];
    const float* be_m1  = (const float*)d_in[17];
    const float* W_m2   = (const float*)d_in[18];
    const float* g_m2   = (const float*)d_in[19];
    const float* be_m2  = (const float*)d_in[20];

    int Nt = in_sizes[1] / 128;
    int E  = in_sizes[4];
    float* outp = (float*)d_out;

    char* w = (char*)d_ws;
    size_t off = 0;
    auto alloc = [&](size_t bytes) { char* p = w + off;
        off = (off + bytes + 255) & ~(size_t)255; return p; };
    float*  tf     = (float*) alloc((size_t)Nt * 128 * sizeof(float));
    bf16_t* sw     = (bf16_t*)alloc(98304 * sizeof(bf16_t));
    bf16_t* ctx    = (bf16_t*)alloc((size_t)E * 128 * sizeof(bf16_t));
    int*    start  = (int*)   alloc((size_t)Nt * sizeof(int));
    int*    cursor = (int*)   alloc((size_t)Nt * sizeof(int));
    int*    perm   = (int*)   alloc((size_t)E * sizeof(int));
    int*    bsum   = (int*)   alloc(128 * sizeof(int));

    bf16_t* swIn = sw;
    bf16_t* swM1 = sw + 16384;
    bf16_t* swM2 = sw + 32768;
    bf16_t* swC1 = sw + 49152;
    bf16_t* swC2 = sw + 81920;

    int NB = (Nt + 1023) / 1024;

    k_prep<<<384, 256, 0, stream>>>(W_in, W_m1, W_m2, W_ctx1, W_ctx2, sw);
    // CSR build
    k_zero<<<(Nt + 255) / 256, 256, 0, stream>>>(start, Nt);
    k_hist<<<(E + 255) / 256, 256, 0, stream>>>(wi, start, E);
    k_scan_block<<<NB, 256, 0, stream>>>(start, bsum, Nt);
    k_scan_top<<<1, 128, 0, stream>>>(bsum, NB);
    k_scan_add<<<(Nt + 255) / 256, 256, 0, stream>>>(start, cursor, bsum, Nt);
    k_bucket<<<(E + 255) / 256, 256, 0, stream>>>(wi, cursor, perm, E);
    // main pipeline
    k_gemm_in<<<(Nt + 63) / 64, 256, 0, stream>>>(tfeat, swIn, tf, Nt);
    k_edge<<<(E + 31) / 32, 64, 0, stream>>>(cfeat, cpose, tpose, hi, wi,
                                             W_rp, b_rp, g_ctx, be_ctx,
                                             swC1, swC2, perm, ctx, E);
    k_out<<<(Nt + 63) / 64, 256, 0, stream>>>(tf, tfeat, start, cursor, ctx,
                                              g_n, be_n, g_m1, be_m1,
                                              g_m2, be_m2, swM1, swM2, outp, Nt);
}